// Round 1
// baseline (163.406 us; speedup 1.0000x reference)
//
#include <hip/hip_runtime.h>
#include <math.h>

#define F 8
#define C 4096
#define NOFF 28             // i<j factor pairs (diag G_ii is closed-form)
#define NPAIR 36            // i<=j pairs
#define EPSF 1e-8f

#define QCHUNK 64           // q per block (broadcast from 2 KB LDS)
#define NCHUNK (C / QCHUNK) // 64
#define PBLK 256            // p per block, one per thread
#define NPB (C / PBLK)      // 16
#define NBLK (NPB * NCHUNK) // 1024 blocks = 4/CU

#define ACC_N 96
#define NBANK 8
#define WS_S (F * C)                      // s[8][4096] row sums
#define WS_TOTAL (WS_S + NBANK * ACC_N)   // 33536 floats ~= 131 KB

__device__ __forceinline__ float wave_reduce(float v) {
    #pragma unroll
    for (int off = 32; off > 0; off >>= 1) v += __shfl_down(v, off, 64);
    return v;
}

__global__ __launch_bounds__(256) void zero_kernel(float* __restrict__ ws) {
    const int i = blockIdx.x * 256 + threadIdx.x;
    if (i < WS_TOTAL) ws[i] = 0.0f;
}

// Each lane owns one p; q values are wave-uniform broadcasts from LDS.
// Per 4-q group: 8 ds_read_b128 (broadcast) + 32 sub + 32 add + 112 FMA
// covering 256 (p,q) pairs. Off-diagonal Gram terms only; row sums s_f(p)
// accumulate per-lane and go to global via one atomicAdd per factor.
__global__ __launch_bounds__(256, 4) void pair_kernel(const float* __restrict__ x,
                                                      float* __restrict__ s,
                                                      float* __restrict__ acc) {
    __shared__ __align__(16) float xs[F * QCHUNK];   // 2 KB
    const int tid  = threadIdx.x;
    const int lane = tid & 63;
    const int wave = tid >> 6;
    const int pb   = blockIdx.x & (NPB - 1);
    const int qc   = blockIdx.x >> 4;                // NPB == 16
    const int p    = pb * PBLK + tid;

    // stage q-chunk: 8 factors x 64 floats = 128 float4, coalesced
    if (tid < F * (QCHUNK / 4)) {
        const int f  = tid >> 4;                     // / (QCHUNK/4)
        const int q4 = tid & (QCHUNK / 4 - 1);
        ((float4*)xs)[tid] = ((const float4*)x)[f * (C / 4) + qc * (QCHUNK / 4) + q4];
    }

    float xp[F];
    #pragma unroll
    for (int f = 0; f < F; ++f) xp[f] = x[f * C + p];

    float g[NOFF];
    #pragma unroll
    for (int k = 0; k < NOFF; ++k) g[k] = 0.0f;
    float rs[F];
    #pragma unroll
    for (int f = 0; f < F; ++f) rs[f] = 0.0f;

    __syncthreads();                                 // only barrier before epilogue

    #pragma unroll 4
    for (int g4 = 0; g4 < QCHUNK / 4; ++g4) {
        float a0[F], a1[F], a2[F], a3[F];
        #pragma unroll
        for (int f = 0; f < F; ++f) {
            const float4 v = ((const float4*)xs)[f * (QCHUNK / 4) + g4];  // broadcast
            a0[f] = __builtin_fabsf(v.x - xp[f]);
            a1[f] = __builtin_fabsf(v.y - xp[f]);
            a2[f] = __builtin_fabsf(v.z - xp[f]);
            a3[f] = __builtin_fabsf(v.w - xp[f]);
            rs[f] += (a0[f] + a1[f]) + (a2[f] + a3[f]);
        }
        int k = 0;
        #pragma unroll
        for (int i = 0; i < F; ++i) {
            #pragma unroll
            for (int j = i + 1; j < F; ++j) {
                g[k] = __builtin_fmaf(a0[i], a0[j], g[k]);
                g[k] = __builtin_fmaf(a1[i], a1[j], g[k]);
                g[k] = __builtin_fmaf(a2[i], a2[j], g[k]);
                g[k] = __builtin_fmaf(a3[i], a3[j], g[k]);
                ++k;
            }
        }
    }

    // row-sum partials: per-lane scalars, one device atomic per factor
    #pragma unroll
    for (int f = 0; f < F; ++f) atomicAdd(&s[f * C + p], rs[f]);

    // reduce off-diag Gram partials: lanes -> waves -> banked global atomics
    #pragma unroll
    for (int k = 0; k < NOFF; ++k) g[k] = wave_reduce(g[k]);

    __syncthreads();                                 // done reading xs; reuse
    float* red = xs;                                 // [4][NOFF]
    if (lane == 0) {
        #pragma unroll
        for (int k = 0; k < NOFF; ++k) red[wave * NOFF + k] = g[k];
    }
    __syncthreads();
    if (tid < NOFF) {
        const float v = red[tid] + red[NOFF + tid] + red[2 * NOFF + tid] + red[3 * NOFF + tid];
        atomicAdd(acc + (blockIdx.x & (NBANK - 1)) * ACC_N + tid, v);
    }
}

// Merged: s-reduction (D/T) + moment pass (Q/T0 for closed-form G_ii) + final
// scalar epilogue, in one 1024-thread block (reads 256 KB, L2-resident).
__global__ __launch_bounds__(1024) void finish_kernel(const float* __restrict__ x,
                                                      const float* __restrict__ s,
                                                      const float* __restrict__ acc,
                                                      float* __restrict__ out) {
    __shared__ float red[16 * 60];
    __shared__ float A[ACC_N];   // [0,28): OG  [28,64): D  [64,72): T  [72,80): Q  [80,88): T0
    const int tid  = threadIdx.x;
    const int lane = tid & 63;
    const int wave = tid >> 6;

    float vals[60];              // D[36] | T[8] | Q[8] | T0[8]
    #pragma unroll
    for (int k = 0; k < 60; ++k) vals[k] = 0.0f;

    #pragma unroll
    for (int r = 0; r < C / 1024; ++r) {
        const int p = r * 1024 + tid;
        float sv[F], xv[F];
        #pragma unroll
        for (int f = 0; f < F; ++f) { sv[f] = s[f * C + p]; xv[f] = x[f * C + p]; }
        int k = 0;
        #pragma unroll
        for (int i = 0; i < F; ++i) {
            #pragma unroll
            for (int j = i; j < F; ++j) { vals[k] = __builtin_fmaf(sv[i], sv[j], vals[k]); ++k; }
        }
        #pragma unroll
        for (int f = 0; f < F; ++f) vals[36 + f] += sv[f];
        #pragma unroll
        for (int f = 0; f < F; ++f) vals[44 + f] = __builtin_fmaf(xv[f], xv[f], vals[44 + f]);
        #pragma unroll
        for (int f = 0; f < F; ++f) vals[52 + f] += xv[f];
    }
    #pragma unroll
    for (int k = 0; k < 60; ++k) vals[k] = wave_reduce(vals[k]);
    if (lane == 0) {
        #pragma unroll
        for (int k = 0; k < 60; ++k) red[wave * 60 + k] = vals[k];
    }
    __syncthreads();
    if (tid < 60) {
        float v = 0.0f;
        #pragma unroll
        for (int w = 0; w < 16; ++w) v += red[w * 60 + tid];
        A[28 + tid] = v;
    }
    if (tid >= 64 && tid < 64 + NOFF) {
        const int k = tid - 64;
        float v = 0.0f;
        #pragma unroll
        for (int b = 0; b < NBANK; ++b) v += acc[b * ACC_N + k];
        A[k] = v;
    }
    __syncthreads();
    if (tid == 0) {
        const float invC  = 1.0f / (float)C;   // 2^-12, exact
        const float invC2 = invC * invC;       // 2^-24, exact
        float dcov[NPAIR], diag[F];
        int k = 0, ko = 0;
        for (int i = 0; i < F; ++i)
            for (int j = i; j < F; ++j) {
                float G;
                if (i == j) {
                    // closed form: sum_pq (x_p - x_q)^2 = 2C*sum(x^2) - 2*(sum x)^2
                    G = 2.0f * (float)C * A[72 + i] - 2.0f * A[80 + i] * A[80 + i];
                } else {
                    G = A[ko]; ++ko;
                }
                // S_ij = G/C^2 - 2 D/C^3 + T_i T_j / C^4
                const float S = G * invC2 - 2.0f * A[28 + k] * invC2 * invC
                              + (A[64 + i] * invC2) * (A[64 + j] * invC2);
                const float dc = __builtin_amdgcn_sqrtf(fmaxf(S, 0.0f) + EPSF);
                dcov[k] = dc;
                if (i == j) diag[i] = dc;
                ++k;
            }
        float cor = 0.0f;
        k = 0;
        for (int i = 0; i < F; ++i)
            for (int j = i; j < F; ++j) {
                if (j > i)
                    cor += dcov[k] * __builtin_amdgcn_rcpf(
                               __builtin_amdgcn_sqrtf(diag[i] * diag[j] + EPSF));
                ++k;
            }
        out[0] = cor;
    }
}

extern "C" void kernel_launch(void* const* d_in, const int* in_sizes, int n_in,
                              void* d_out, int out_size, void* d_ws, size_t ws_size,
                              hipStream_t stream) {
    const float* x = (const float*)d_in[0];
    float* s   = (float*)d_ws;            // 8*4096 row sums
    float* acc = s + WS_S;                // 8 banks * 96 floats
    float* out = (float*)d_out;

    hipLaunchKernelGGL(zero_kernel,   dim3((WS_TOTAL + 255) / 256), dim3(256), 0, stream, (float*)d_ws);
    hipLaunchKernelGGL(pair_kernel,   dim3(NBLK), dim3(256),  0, stream, x, s, acc);
    hipLaunchKernelGGL(finish_kernel, dim3(1),    dim3(1024), 0, stream, x, s, acc, out);
}

// Round 2
// 105.303 us; speedup vs baseline: 1.5518x; 1.5518x over previous
//
#include <hip/hip_runtime.h>
#include <math.h>

#define F 8
#define C 4096
#define NOFF 28             // i<j factor pairs (diag G_ii is closed-form)
#define NPAIR 36            // i<=j pairs
#define EPSF 1e-8f

#define QCHUNK 64           // q per block (broadcast from 2 KB LDS)
#define NCHUNK (C / QCHUNK) // 64
#define PBLK 256            // p per block, one per thread
#define NPB (C / PBLK)      // 16
#define NBLK (NPB * NCHUNK) // 1024 blocks = 4/CU

// acc layout (per bank): G_offdiag[28] | D[36] | T[8] | Q[8] | T0[8] -> 88, pad 96
#define ACC_G  0
#define ACC_D  28
#define ACC_T  64
#define ACC_Q  72
#define ACC_T0 80
#define ACC_N  96
#define NBANK  8

// ws layout: part[NCHUNK][F][C] row-sum partials (8 MB), then acc banks (3 KB)
#define WS_PART (NCHUNK * F * C)

__device__ __forceinline__ float wave_reduce(float v) {
    #pragma unroll
    for (int off = 32; off > 0; off >>= 1) v += __shfl_down(v, off, 64);
    return v;
}

// Each lane owns one p; q values are wave-uniform broadcasts from LDS.
// Row-sum partials go out as PLAIN coalesced stores (no atomics) to
// part[qc][f][p]; only the 28 off-diag Gram scalars use (banked) atomics.
__global__ __launch_bounds__(256) void pair_kernel(const float* __restrict__ x,
                                                   float* __restrict__ part,
                                                   float* __restrict__ acc) {
    __shared__ __align__(16) float xs[F * QCHUNK];   // 2 KB
    const int tid  = threadIdx.x;
    const int lane = tid & 63;
    const int wave = tid >> 6;
    const int pb   = blockIdx.x & (NPB - 1);
    const int qc   = blockIdx.x >> 4;                // NPB == 16
    const int p    = pb * PBLK + tid;

    // stage q-chunk: 8 factors x 64 floats = 128 float4, coalesced
    if (tid < F * (QCHUNK / 4)) {
        const int f  = tid >> 4;                     // / (QCHUNK/4)
        const int q4 = tid & (QCHUNK / 4 - 1);
        ((float4*)xs)[tid] = ((const float4*)x)[f * (C / 4) + qc * (QCHUNK / 4) + q4];
    }

    float xp[F];
    #pragma unroll
    for (int f = 0; f < F; ++f) xp[f] = x[f * C + p];

    float g[NOFF];
    #pragma unroll
    for (int k = 0; k < NOFF; ++k) g[k] = 0.0f;
    float rs[F];
    #pragma unroll
    for (int f = 0; f < F; ++f) rs[f] = 0.0f;

    __syncthreads();                                 // only barrier before epilogue

    #pragma unroll 4
    for (int g4 = 0; g4 < QCHUNK / 4; ++g4) {
        float a0[F], a1[F], a2[F], a3[F];
        #pragma unroll
        for (int f = 0; f < F; ++f) {
            const float4 v = ((const float4*)xs)[f * (QCHUNK / 4) + g4];  // broadcast
            a0[f] = __builtin_fabsf(v.x - xp[f]);
            a1[f] = __builtin_fabsf(v.y - xp[f]);
            a2[f] = __builtin_fabsf(v.z - xp[f]);
            a3[f] = __builtin_fabsf(v.w - xp[f]);
            rs[f] += (a0[f] + a1[f]) + (a2[f] + a3[f]);
        }
        int k = 0;
        #pragma unroll
        for (int i = 0; i < F; ++i) {
            #pragma unroll
            for (int j = i + 1; j < F; ++j) {
                g[k] = __builtin_fmaf(a0[i], a0[j], g[k]);
                g[k] = __builtin_fmaf(a1[i], a1[j], g[k]);
                g[k] = __builtin_fmaf(a2[i], a2[j], g[k]);
                g[k] = __builtin_fmaf(a3[i], a3[j], g[k]);
                ++k;
            }
        }
    }

    // row-sum partials: plain coalesced stores, no atomics, no RMW traffic
    #pragma unroll
    for (int f = 0; f < F; ++f) part[(qc * F + f) * C + p] = rs[f];

    // reduce off-diag Gram partials: lanes -> waves -> banked global atomics
    #pragma unroll
    for (int k = 0; k < NOFF; ++k) g[k] = wave_reduce(g[k]);

    __syncthreads();                                 // done reading xs; reuse
    float* red = xs;                                 // [4][NOFF]
    if (lane == 0) {
        #pragma unroll
        for (int k = 0; k < NOFF; ++k) red[wave * NOFF + k] = g[k];
    }
    __syncthreads();
    if (tid < NOFF) {
        const float v = red[tid] + red[NOFF + tid] + red[2 * NOFF + tid] + red[3 * NOFF + tid];
        atomicAdd(acc + (blockIdx.x & (NBANK - 1)) * ACC_N + ACC_G + tid, v);
    }
}

// One thread per p: reduce the 64 q-chunk row-sum partials -> full s_f(p),
// then form D_ij = s_i s_j, T_f = sum s_f, and the x-moments Q/T0 for the
// closed-form diagonal Gram. 60 scalars per block via banked atomics.
__global__ __launch_bounds__(256) void sred_kernel(const float* __restrict__ x,
                                                   const float* __restrict__ part,
                                                   float* __restrict__ acc) {
    __shared__ float red[4 * 60];
    const int tid  = threadIdx.x;
    const int lane = tid & 63;
    const int wave = tid >> 6;
    const int p    = blockIdx.x * 256 + tid;

    float sv[F];
    #pragma unroll
    for (int f = 0; f < F; ++f) sv[f] = 0.0f;
    #pragma unroll 2
    for (int qc = 0; qc < NCHUNK; ++qc) {
        #pragma unroll
        for (int f = 0; f < F; ++f) sv[f] += part[(qc * F + f) * C + p];
    }

    float xv[F];
    #pragma unroll
    for (int f = 0; f < F; ++f) xv[f] = x[f * C + p];

    float vals[60];              // D[36] | T[8] | Q[8] | T0[8]
    int k = 0;
    #pragma unroll
    for (int i = 0; i < F; ++i)
        #pragma unroll
        for (int j = i; j < F; ++j) { vals[k] = sv[i] * sv[j]; ++k; }
    #pragma unroll
    for (int f = 0; f < F; ++f) vals[36 + f] = sv[f];
    #pragma unroll
    for (int f = 0; f < F; ++f) vals[44 + f] = xv[f] * xv[f];
    #pragma unroll
    for (int f = 0; f < F; ++f) vals[52 + f] = xv[f];

    #pragma unroll
    for (int k2 = 0; k2 < 60; ++k2) vals[k2] = wave_reduce(vals[k2]);
    if (lane == 0) {
        #pragma unroll
        for (int k2 = 0; k2 < 60; ++k2) red[wave * 60 + k2] = vals[k2];
    }
    __syncthreads();
    if (tid < 60) {
        const float v = red[tid] + red[60 + tid] + red[120 + tid] + red[180 + tid];
        atomicAdd(acc + (blockIdx.x & (NBANK - 1)) * ACC_N + ACC_D + tid, v);
    }
}

__global__ __launch_bounds__(128) void finish_kernel(const float* __restrict__ acc,
                                                     float* __restrict__ out) {
    __shared__ float A[ACC_N];
    const int tid = threadIdx.x;
    if (tid < 88) {
        float s = 0.0f;
        #pragma unroll
        for (int b = 0; b < NBANK; ++b) s += acc[b * ACC_N + tid];
        A[tid] = s;
    }
    __syncthreads();
    if (tid == 0) {
        const float invC  = 1.0f / (float)C;   // 2^-12, exact
        const float invC2 = invC * invC;       // 2^-24, exact
        float dcov[NPAIR], diag[F];
        int k = 0, ko = 0;
        for (int i = 0; i < F; ++i)
            for (int j = i; j < F; ++j) {
                float G;
                if (i == j) {
                    // closed form: sum_pq (x_p - x_q)^2 = 2C*sum(x^2) - 2*(sum x)^2
                    G = 2.0f * (float)C * A[ACC_Q + i] - 2.0f * A[ACC_T0 + i] * A[ACC_T0 + i];
                } else {
                    G = A[ACC_G + ko]; ++ko;
                }
                // S_ij = G/C^2 - 2 D/C^3 + T_i T_j / C^4
                const float S = G * invC2 - 2.0f * A[ACC_D + k] * invC2 * invC
                              + (A[ACC_T + i] * invC2) * (A[ACC_T + j] * invC2);
                const float dc = __builtin_amdgcn_sqrtf(fmaxf(S, 0.0f) + EPSF);
                dcov[k] = dc;
                if (i == j) diag[i] = dc;
                ++k;
            }
        float cor = 0.0f;
        k = 0;
        for (int i = 0; i < F; ++i)
            for (int j = i; j < F; ++j) {
                if (j > i)
                    cor += dcov[k] * __builtin_amdgcn_rcpf(
                               __builtin_amdgcn_sqrtf(diag[i] * diag[j] + EPSF));
                ++k;
            }
        out[0] = cor;
    }
}

extern "C" void kernel_launch(void* const* d_in, const int* in_sizes, int n_in,
                              void* d_out, int out_size, void* d_ws, size_t ws_size,
                              hipStream_t stream) {
    const float* x = (const float*)d_in[0];
    float* part = (float*)d_ws;               // 8 MB of row-sum partials
    float* acc  = part + WS_PART;             // 8 banks * 96 floats
    float* out  = (float*)d_out;

    hipMemsetAsync(acc, 0, NBANK * ACC_N * sizeof(float), stream);
    hipLaunchKernelGGL(pair_kernel,   dim3(NBLK), dim3(256), 0, stream, x, part, acc);
    hipLaunchKernelGGL(sred_kernel,   dim3(NPB),  dim3(256), 0, stream, x, part, acc);
    hipLaunchKernelGGL(finish_kernel, dim3(1),    dim3(128), 0, stream, acc, out);
}